// Round 3
// baseline (78.632 us; speedup 1.0000x reference)
//
#include <hip/hip_runtime.h>
#include <math.h>

#define CH_EPS   1e-6f
#define CH_N     4096
#define CH_BS    8
#define CH_JCH   512                 // j-chunk per block
#define CH_NJC   (CH_N / CH_JCH)     // 8 chunks
#define CH_PTS   (CH_BS * CH_N)      // 32768 points per array

// ws layout (floats):
//   q4   : float4[2][CH_BS][CH_N]      -> 65536 float4 = 262144 floats (1 MB)
//   part : float [2][CH_BS][CH_NJC][CH_N] -> 524288 floats (2 MB)
#define WS_Q4_F4   ((size_t)2 * CH_PTS)
#define WS_PART_OF ((size_t)WS_Q4_F4 * 4)

// ---------- Kernel A: pack {q, |q|^2} as float4 for both arrays ----------
__global__ __launch_bounds__(256) void chamfer_pack_kernel(
    const float* __restrict__ x, const float* __restrict__ y,
    float4* __restrict__ q4) {
    const int idx = blockIdx.x * 256 + threadIdx.x;    // [0, 65536)
    const int arr = idx >> 15;                          // 0:x 1:y
    const int e   = idx & (CH_PTS - 1);
    const float* src = arr ? y : x;
    const float a = src[e * 3 + 0];
    const float b = src[e * 3 + 1];
    const float c = src[e * 3 + 2];
    q4[idx] = make_float4(a, b, c, a * a + b * b + c * c);
}

// ---------- Kernel B: per (i-tile, j-chunk) partial min of (|q|^2 - 2 p.q) ----------
// dir 0: own=y, other=x ; dir 1: own=x, other=y
__global__ __launch_bounds__(256) void chamfer_scan_kernel(
    const float* __restrict__ x, const float* __restrict__ y,
    const float4* __restrict__ q4, float* __restrict__ part) {
    const int tid = threadIdx.x;
    const int it  = blockIdx.x >> 3;       // i-tile [0,16)
    const int jc  = blockIdx.x & 7;        // j-chunk [0,8)
    const int i   = it * 256 + tid;
    const int b   = blockIdx.y;
    const int dir = blockIdx.z;

    const float* own = (dir == 0) ? y : x;
    const float* op  = own + ((size_t)b * CH_N + i) * 3;
    const float px = op[0], py = op[1], pz = op[2];
    const float p2 = px * px + py * py + pz * pz;
    const float nx = -2.0f * px, ny = -2.0f * py, nz = -2.0f * pz;

    // other set, packed: q4 + dir-select base
    const float4* __restrict__ qc =
        q4 + ((size_t)(dir == 0 ? 0 : 1) * CH_PTS + (size_t)b * CH_N + (size_t)jc * CH_JCH);

    float mm[8];
#pragma unroll
    for (int k = 0; k < 8; ++k) mm[k] = 3.4e38f;

    float4 cur[8], nxt[8];
#pragma unroll
    for (int k = 0; k < 8; ++k) cur[k] = qc[k];

    for (int j0 = 0; j0 < CH_JCH - 8; j0 += 8) {
#pragma unroll
        for (int k = 0; k < 8; ++k) nxt[k] = qc[j0 + 8 + k];
#pragma unroll
        for (int k = 0; k < 8; ++k) {
            const float t = fmaf(nx, cur[k].x,
                            fmaf(ny, cur[k].y,
                            fmaf(nz, cur[k].z, cur[k].w)));
            mm[k] = fminf(mm[k], t);
        }
#pragma unroll
        for (int k = 0; k < 8; ++k) cur[k] = nxt[k];
    }
    // epilogue: last 8
#pragma unroll
    for (int k = 0; k < 8; ++k) {
        const float t = fmaf(nx, cur[k].x,
                        fmaf(ny, cur[k].y,
                        fmaf(nz, cur[k].z, cur[k].w)));
        mm[k] = fminf(mm[k], t);
    }

    const float m = fminf(fminf(fminf(mm[0], mm[1]), fminf(mm[2], mm[3])),
                          fminf(fminf(mm[4], mm[5]), fminf(mm[6], mm[7])));

    // distinct slot per (dir,b,jc,i): no atomics, no init needed
    part[(((size_t)dir * CH_BS + b) * CH_NJC + jc) * CH_N + i] = m + p2;
}

// ---------- Kernel C: finalize — min over chunks, sqrt, mean ----------
__global__ __launch_bounds__(256) void chamfer_finalize_kernel(
    const float* __restrict__ part, float* __restrict__ out) {
    const int b = blockIdx.x;
    const int tid = threadIdx.x;

    float s = 0.0f;
    for (int k = tid; k < 2 * CH_N; k += 256) {
        const int dir = k >> 12;
        const int i   = k & (CH_N - 1);
        const size_t base = (((size_t)dir * CH_BS + b) * CH_NJC) * CH_N + i;
        float m = part[base];
#pragma unroll
        for (int jc = 1; jc < CH_NJC; ++jc)
            m = fminf(m, part[base + (size_t)jc * CH_N]);
        s += sqrtf(CH_EPS + fmaxf(m, 0.0f));
    }
    s *= (1.0f / (float)CH_N);

#pragma unroll
    for (int off = 32; off > 0; off >>= 1) s += __shfl_down(s, off, 64);

    __shared__ float wsum[4];
    if ((tid & 63) == 0) wsum[tid >> 6] = s;
    __syncthreads();
    if (tid == 0) out[b] = wsum[0] + wsum[1] + wsum[2] + wsum[3];
}

extern "C" void kernel_launch(void* const* d_in, const int* in_sizes, int n_in,
                              void* d_out, int out_size, void* d_ws, size_t ws_size,
                              hipStream_t stream) {
    const float* x = (const float*)d_in[0];
    const float* y = (const float*)d_in[1];
    float* out = (float*)d_out;
    float4* q4  = (float4*)d_ws;
    float* part = (float*)d_ws + WS_PART_OF;

    // A: pack q + |q|^2  (65536 points)
    chamfer_pack_kernel<<<dim3(2 * CH_PTS / 256), dim3(256), 0, stream>>>(x, y, q4);

    // B: scan  (16 i-tiles x 8 j-chunks, 8 batches, 2 dirs)
    chamfer_scan_kernel<<<dim3(16 * CH_NJC, CH_BS, 2), dim3(256), 0, stream>>>(x, y, q4, part);

    // C: finalize (one block per batch)
    chamfer_finalize_kernel<<<dim3(CH_BS), dim3(256), 0, stream>>>(part, out);
}

// Round 4
// 30.843 us; speedup vs baseline: 2.5494x; 2.5494x over previous
//
#include <hip/hip_runtime.h>
#include <math.h>

#define CH_EPS 1e-6f
#define CH_N   4096
#define CH_BS  8
#define CH_JC  8                   // j-chunks
#define CH_JCH (CH_N / CH_JC)      // 512 points per chunk
// block = 256 threads, TI=2 own points/thread -> 512 i per block, 8 i-tiles

// part[dir][b][jc][i] : 2*8*8*4096 floats = 2 MB in d_ws
#define PART_IDX(dir, b, jc, i) \
    ((((size_t)(dir) * CH_BS + (b)) * CH_JC + (jc)) * CH_N + (i))

// ---------------- scan: per (i-tile, j-chunk) partial min ----------------
// dir 0: own=y, other=x ; dir 1: own=x, other=y
// d2 = p2 + (q2 - 2 p.q); track min over j of (q2 - 2 p.q), add p2 at end.
__global__ __launch_bounds__(256) void chamfer_scan_kernel(
    const float* __restrict__ x, const float* __restrict__ y,
    float* __restrict__ part, float* __restrict__ out) {
    const int tid = threadIdx.x;
    const int it  = blockIdx.x >> 3;   // i-tile [0,8)
    const int jc  = blockIdx.x & 7;    // j-chunk [0,8)
    const int b   = blockIdx.y;
    const int dir = blockIdx.z;

    // zero the output once per call (finalize dispatch runs after us)
    if (blockIdx.x == 0 && b == 0 && dir == 0 && tid < CH_BS) out[tid] = 0.0f;

    const float* own   = dir ? x : y;
    const float* other = dir ? y : x;

    // ---- stage j-chunk into LDS as {q, |q|^2} ----
    __shared__ float4 q4s[CH_JCH];   // 8 KB
    {
        const float* qsrc = other + ((size_t)b * CH_N + (size_t)jc * CH_JCH) * 3;
        const int p0 = tid * 2;      // 2 points per thread
        const float a0 = qsrc[p0 * 3 + 0], b0 = qsrc[p0 * 3 + 1], c0 = qsrc[p0 * 3 + 2];
        const float a1 = qsrc[p0 * 3 + 3], b1 = qsrc[p0 * 3 + 4], c1 = qsrc[p0 * 3 + 5];
        q4s[p0]     = make_float4(a0, b0, c0, a0 * a0 + b0 * b0 + c0 * c0);
        q4s[p0 + 1] = make_float4(a1, b1, c1, a1 * a1 + b1 * b1 + c1 * c1);
    }
    __syncthreads();

    // ---- own points (TI=2, stride 256 keeps part writes coalesced) ----
    const int i0 = it * 512 + tid;
    const int i1 = i0 + 256;
    const float* op0 = own + ((size_t)b * CH_N + i0) * 3;
    const float* op1 = own + ((size_t)b * CH_N + i1) * 3;
    const float px0 = op0[0], py0 = op0[1], pz0 = op0[2];
    const float px1 = op1[0], py1 = op1[1], pz1 = op1[2];
    const float p20 = px0 * px0 + py0 * py0 + pz0 * pz0;
    const float p21 = px1 * px1 + py1 * py1 + pz1 * pz1;
    const float nx0 = -2.0f * px0, ny0 = -2.0f * py0, nz0 = -2.0f * pz0;
    const float nx1 = -2.0f * px1, ny1 = -2.0f * py1, nz1 = -2.0f * pz1;

    float m0[4], m1[4];
#pragma unroll
    for (int k = 0; k < 4; ++k) { m0[k] = 3.4e38f; m1[k] = 3.4e38f; }

    // ---- inner scan: 8 ds_read_b128 feed 64 VALU ops per step ----
    for (int j0 = 0; j0 < CH_JCH; j0 += 8) {
        float4 qv[8];
#pragma unroll
        for (int k = 0; k < 8; ++k) qv[k] = q4s[j0 + k];
#pragma unroll
        for (int k = 0; k < 8; ++k) {
            const float t0 = fmaf(nx0, qv[k].x,
                             fmaf(ny0, qv[k].y,
                             fmaf(nz0, qv[k].z, qv[k].w)));
            const float t1 = fmaf(nx1, qv[k].x,
                             fmaf(ny1, qv[k].y,
                             fmaf(nz1, qv[k].z, qv[k].w)));
            m0[k & 3] = fminf(m0[k & 3], t0);
            m1[k & 3] = fminf(m1[k & 3], t1);
        }
    }

    const float r0 = fminf(fminf(m0[0], m0[1]), fminf(m0[2], m0[3])) + p20;
    const float r1 = fminf(fminf(m1[0], m1[1]), fminf(m1[2], m1[3])) + p21;

    part[PART_IDX(dir, b, jc, i0)] = r0;
    part[PART_IDX(dir, b, jc, i1)] = r1;
}

// ---------------- finalize: min over chunks, sqrt, mean, accumulate ----------------
// grid (CH_BS, 8 slices); out was zeroed by the scan dispatch.
__global__ __launch_bounds__(256) void chamfer_finalize_kernel(
    const float* __restrict__ part, float* __restrict__ out) {
    const int b   = blockIdx.x;
    const int sl  = blockIdx.y;
    const int tid = threadIdx.x;

    float s = 0.0f;
#pragma unroll
    for (int dir = 0; dir < 2; ++dir) {
#pragma unroll
        for (int r = 0; r < 2; ++r) {
            const int i = sl * 512 + r * 256 + tid;
            const size_t base = PART_IDX(dir, b, 0, i);
            float m = part[base];
#pragma unroll
            for (int jc = 1; jc < CH_JC; ++jc)
                m = fminf(m, part[base + (size_t)jc * CH_N]);
            s += sqrtf(CH_EPS + fmaxf(m, 0.0f));
        }
    }
    s *= (1.0f / (float)CH_N);

#pragma unroll
    for (int off = 32; off > 0; off >>= 1) s += __shfl_down(s, off, 64);

    __shared__ float wsum[4];
    if ((tid & 63) == 0) wsum[tid >> 6] = s;
    __syncthreads();
    if (tid == 0) atomicAdd(out + b, wsum[0] + wsum[1] + wsum[2] + wsum[3]);
}

extern "C" void kernel_launch(void* const* d_in, const int* in_sizes, int n_in,
                              void* d_out, int out_size, void* d_ws, size_t ws_size,
                              hipStream_t stream) {
    const float* x = (const float*)d_in[0];
    const float* y = (const float*)d_in[1];
    float* out  = (float*)d_out;
    float* part = (float*)d_ws;

    // scan: 8 i-tiles x 8 j-chunks, 8 batches, 2 dirs = 1024 blocks
    chamfer_scan_kernel<<<dim3(64, CH_BS, 2), dim3(256), 0, stream>>>(x, y, part, out);

    // finalize: 64 blocks
    chamfer_finalize_kernel<<<dim3(CH_BS, 8), dim3(256), 0, stream>>>(part, out);
}